// Round 1
// baseline (1514.084 us; speedup 1.0000x reference)
//
#include <hip/hip_runtime.h>
#include <hip/hip_bf16.h>
#include <cstdio>

#define TPB 256
#define B_ 4
#define H_ 128
#define W_ 128
#define D_ 768
#define FW 65
#define BH_ 512                  // B_*H_
#define THRESH_ 0.01f
#define NEG_TWO_PI_OVER_128 (-0.04908738521234052f)

// freq buffer layout (in d_ws): float2[(bh*65 + fw)*768 + d]
// point-block P in [0, 512*65*8): base float2 offset = P*96  (since 768 = 8*96)

// ---------------------------------------------------------------------------
// K1a: forward FFT over W (real input), keep bins 0..64, scale 1/128.
// grid: (512, 12), LDS: re/im [128][64] + twiddle[2][64]
// DIF: natural-in, bit-reversed-out; we gather bitrev at the write.
// ---------------------------------------------------------------------------
__global__ __launch_bounds__(TPB) void k_fwd_w(const float* __restrict__ x,
                                               float2* __restrict__ fq) {
  extern __shared__ float sm[];
  float* re  = sm;
  float* im  = sm + 8192;
  float* twr = sm + 16384;
  float* twi = sm + 16448;
  const int t  = threadIdx.x;
  const int bh = blockIdx.x;
  const int d0 = blockIdx.y << 6;
  if (t < 64) { float s, c; __sincosf(NEG_TWO_PI_OVER_128 * (float)t, &s, &c); twr[t] = c; twi[t] = s; }
  const float* xp = x + (size_t)bh * (W_ * D_) + d0;
  const int dd = t & 63, r4 = t >> 6;
  for (int it = 0; it < 32; ++it) {
    const int w = (it << 2) + r4;
    re[(w << 6) + dd] = xp[w * D_ + dd];
    im[(w << 6) + dd] = 0.f;
  }
  __syncthreads();
  for (int s = 0; s < 7; ++s) {
    const int half = 64 >> s;
    for (int it = 0; it < 16; ++it) {
      const int g = it * TPB + t;
      const int d2 = g & 63, m = g >> 6;
      const int blk = m >> (6 - s), k = m & (half - 1);
      const int ia = (blk << (7 - s)) + k, ib = ia + half;
      const float tr = twr[k << s], ti = twi[k << s];
      const int pa = (ia << 6) + d2, pb = (ib << 6) + d2;
      const float arr = re[pa], aii = im[pa];
      const float brr = re[pb], bii = im[pb];
      re[pa] = arr + brr; im[pa] = aii + bii;
      const float dr = arr - brr, di = aii - bii;
      re[pb] = dr * tr - di * ti;
      im[pb] = dr * ti + di * tr;
    }
    __syncthreads();
  }
  const float sc = 0.0078125f;  // 1/128 (ortho, applied once forward)
  float2* fqp = fq + ((size_t)bh * FW) * D_ + d0;
  for (int it = 0; it < 17; ++it) {
    const int g = it * TPB + t;
    if (g < FW * 64) {
      const int q = g >> 6, d2 = g & 63;
      const int j = __brev((unsigned)q) >> 25;
      fqp[(size_t)q * D_ + d2] = make_float2(re[(j << 6) + d2] * sc, im[(j << 6) + d2] * sc);
    }
  }
}

// ---------------------------------------------------------------------------
// K1b: forward complex FFT over H for the 65 stored columns, in-place.
// Output stays in bit-reversed H order (slot j holds bin bitrev(j)).
// grid: (4, 65, 12)
// ---------------------------------------------------------------------------
__global__ __launch_bounds__(TPB) void k_fwd_h(float2* __restrict__ fq) {
  extern __shared__ float sm[];
  float* re  = sm;
  float* im  = sm + 8192;
  float* twr = sm + 16384;
  float* twi = sm + 16448;
  const int t  = threadIdx.x;
  const int b  = blockIdx.x;
  const int fw = blockIdx.y;
  const int d0 = blockIdx.z << 6;
  if (t < 64) { float s, c; __sincosf(NEG_TWO_PI_OVER_128 * (float)t, &s, &c); twr[t] = c; twi[t] = s; }
  const int dd = t & 63, r4 = t >> 6;
  float2* base = fq + ((size_t)(b * H_) * FW + fw) * D_ + d0;  // h stride = FW*D_
  for (int it = 0; it < 32; ++it) {
    const int h = (it << 2) + r4;
    const float2 v = base[(size_t)h * (FW * D_) + dd];
    re[(h << 6) + dd] = v.x; im[(h << 6) + dd] = v.y;
  }
  __syncthreads();
  for (int s = 0; s < 7; ++s) {
    const int half = 64 >> s;
    for (int it = 0; it < 16; ++it) {
      const int g = it * TPB + t;
      const int d2 = g & 63, m = g >> 6;
      const int blk = m >> (6 - s), k = m & (half - 1);
      const int ia = (blk << (7 - s)) + k, ib = ia + half;
      const float tr = twr[k << s], ti = twi[k << s];
      const int pa = (ia << 6) + d2, pb = (ib << 6) + d2;
      const float arr = re[pa], aii = im[pa];
      const float brr = re[pb], bii = im[pb];
      re[pa] = arr + brr; im[pa] = aii + bii;
      const float dr = arr - brr, di = aii - bii;
      re[pb] = dr * tr - di * ti;
      im[pb] = dr * ti + di * tr;
    }
    __syncthreads();
  }
  for (int it = 0; it < 32; ++it) {
    const int h = (it << 2) + r4;
    base[(size_t)h * (FW * D_) + dd] = make_float2(re[(h << 6) + dd], im[(h << 6) + dd]);
  }
}

// ---------------------------------------------------------------------------
// K2: per-frequency complex MLP (2 layers, shared weights), in-place.
// 64 point-blocks/WG; thread tile = 4 pb x 6 outputs. Hidden as bf16x2.
// LDS: wbuf[96][97] f2 + zbuf[64][97] f2 + bias[96] f2 + hbuf[64][97] u32.
// ---------------------------------------------------------------------------
__global__ __launch_bounds__(TPB) void k_mlp(float2* __restrict__ fq,
    const float* __restrict__ w1r, const float* __restrict__ w1i, const float* __restrict__ b1,
    const float* __restrict__ w2r, const float* __restrict__ w2i, const float* __restrict__ b2) {
  extern __shared__ char smc[];
  float2* wbuf = (float2*)smc;              // 96*97
  float2* zbuf = wbuf + 96 * 97;            // 64*97
  float2* bias = zbuf + 64 * 97;            // 96
  unsigned* hbuf = (unsigned*)(bias + 96);  // 64*97
  const int t  = threadIdx.x;
  const int P0 = blockIdx.x << 6;

  for (int n = t; n < 96 * 96; n += TPB) wbuf[n + n / 96] = make_float2(w1r[n], w1i[n]);
  if (t < 96) bias[t] = make_float2(b1[2 * t], b1[2 * t + 1]);
  {
    const float2* src = fq + (size_t)P0 * 96;
    for (int n = t; n < 64 * 96; n += TPB) zbuf[n + n / 96] = src[n];
  }
  __syncthreads();

  const int og = t & 15, pg = t >> 4;
  float ar[6][4], ai[6][4];
#pragma unroll
  for (int j = 0; j < 6; ++j)
#pragma unroll
    for (int p = 0; p < 4; ++p) { ar[j][p] = 0.f; ai[j][p] = 0.f; }

  for (int i = 0; i < 96; ++i) {
    float zr[4], zi[4];
#pragma unroll
    for (int p = 0; p < 4; ++p) {
      const float2 v = zbuf[(pg * 4 + p) * 97 + i];
      zr[p] = v.x; zi[p] = v.y;
    }
#pragma unroll
    for (int j = 0; j < 6; ++j) {
      const float2 wv = wbuf[(og + 16 * j) * 97 + i];
#pragma unroll
      for (int p = 0; p < 4; ++p) {
        ar[j][p] = fmaf(zr[p], wv.x, fmaf(-zi[p], wv.y, ar[j][p]));
        ai[j][p] = fmaf(zr[p], wv.y, fmaf(zi[p], wv.x, ai[j][p]));
      }
    }
  }
#pragma unroll
  for (int j = 0; j < 6; ++j) {
    const int o = og + 16 * j;
    const float2 bb = bias[o];
#pragma unroll
    for (int p = 0; p < 4; ++p) {
      const float r = fmaxf(ar[j][p] + bb.x, 0.f);
      const float q = fmaxf(ai[j][p] + bb.y, 0.f);
      __hip_bfloat162 hv = __float22bfloat162_rn(make_float2(r, q));
      hbuf[(pg * 4 + p) * 97 + o] = *(unsigned*)&hv;
    }
  }
  __syncthreads();  // all w1/zbuf reads done; hbuf written
  for (int n = t; n < 96 * 96; n += TPB) wbuf[n + n / 96] = make_float2(w2r[n], w2i[n]);
  if (t < 96) bias[t] = make_float2(b2[2 * t], b2[2 * t + 1]);
  __syncthreads();

#pragma unroll
  for (int j = 0; j < 6; ++j)
#pragma unroll
    for (int p = 0; p < 4; ++p) { ar[j][p] = 0.f; ai[j][p] = 0.f; }

  for (int i = 0; i < 96; ++i) {
    float zr[4], zi[4];
#pragma unroll
    for (int p = 0; p < 4; ++p) {
      unsigned u = hbuf[(pg * 4 + p) * 97 + i];
      __hip_bfloat162 hv = *(__hip_bfloat162*)&u;
      const float2 v = __bfloat1622float2(hv);
      zr[p] = v.x; zi[p] = v.y;
    }
#pragma unroll
    for (int j = 0; j < 6; ++j) {
      const float2 wv = wbuf[(og + 16 * j) * 97 + i];
#pragma unroll
      for (int p = 0; p < 4; ++p) {
        ar[j][p] = fmaf(zr[p], wv.x, fmaf(-zi[p], wv.y, ar[j][p]));
        ai[j][p] = fmaf(zr[p], wv.y, fmaf(zi[p], wv.x, ai[j][p]));
      }
    }
  }
#pragma unroll
  for (int j = 0; j < 6; ++j) {
    const int o = og + 16 * j;
    const float2 bb = bias[o];
#pragma unroll
    for (int p = 0; p < 4; ++p) {
      float r = ar[j][p] + bb.x;
      float q = ai[j][p] + bb.y;
      r = (r > THRESH_) ? (r - THRESH_) : ((r < -THRESH_) ? (r + THRESH_) : 0.f);
      q = (q > THRESH_) ? (q - THRESH_) : ((q < -THRESH_) ? (q + THRESH_) : 0.f);
      fq[(size_t)(P0 + pg * 4 + p) * 96 + o] = make_float2(r, q);
    }
  }
}

// ---------------------------------------------------------------------------
// K3a: inverse complex FFT over H (unnormalized). DIT: bit-reversed input
// (exactly what K1b left), natural output. Conjugate twiddles. In-place.
// ---------------------------------------------------------------------------
__global__ __launch_bounds__(TPB) void k_inv_h(float2* __restrict__ fq) {
  extern __shared__ float sm[];
  float* re  = sm;
  float* im  = sm + 8192;
  float* twr = sm + 16384;
  float* twi = sm + 16448;
  const int t  = threadIdx.x;
  const int b  = blockIdx.x;
  const int fw = blockIdx.y;
  const int d0 = blockIdx.z << 6;
  if (t < 64) { float s, c; __sincosf(NEG_TWO_PI_OVER_128 * (float)t, &s, &c); twr[t] = c; twi[t] = s; }
  const int dd = t & 63, r4 = t >> 6;
  float2* base = fq + ((size_t)(b * H_) * FW + fw) * D_ + d0;
  for (int it = 0; it < 32; ++it) {
    const int h = (it << 2) + r4;
    const float2 v = base[(size_t)h * (FW * D_) + dd];
    re[(h << 6) + dd] = v.x; im[(h << 6) + dd] = v.y;
  }
  __syncthreads();
  for (int s = 0; s < 7; ++s) {
    const int half = 1 << s;
    for (int it = 0; it < 16; ++it) {
      const int g = it * TPB + t;
      const int d2 = g & 63, m = g >> 6;
      const int blk = m >> s, k = m & (half - 1);
      const int ia = (blk << (s + 1)) + k, ib = ia + half;
      const int idx = k << (6 - s);
      const float tr = twr[idx], ti = twi[idx];
      const int pa = (ia << 6) + d2, pb = (ib << 6) + d2;
      const float brr = re[pb], bii = im[pb];
      // multiply by conj(table) = e^{+i theta}
      const float xr = brr * tr + bii * ti;
      const float xi = bii * tr - brr * ti;
      const float arr = re[pa], aii = im[pa];
      re[pa] = arr + xr; im[pa] = aii + xi;
      re[pb] = arr - xr; im[pb] = aii - xi;
    }
    __syncthreads();
  }
  for (int it = 0; it < 32; ++it) {
    const int h = (it << 2) + r4;
    base[(size_t)h * (FW * D_) + dd] = make_float2(re[(h << 6) + dd], im[(h << 6) + dd]);
  }
}

// ---------------------------------------------------------------------------
// K3b: Hermitian-extend 65->128 over W, inverse DIF (e^+), take real part,
// scale 1/128, add skip x, write out. grid: (512, 12).
// ---------------------------------------------------------------------------
__global__ __launch_bounds__(TPB) void k_inv_w(const float2* __restrict__ fq,
                                               const float* __restrict__ x,
                                               float* __restrict__ out) {
  extern __shared__ float sm[];
  float* re  = sm;
  float* im  = sm + 8192;
  float* twr = sm + 16384;
  float* twi = sm + 16448;
  const int t  = threadIdx.x;
  const int bh = blockIdx.x;
  const int d0 = blockIdx.y << 6;
  if (t < 64) { float s, c; __sincosf(NEG_TWO_PI_OVER_128 * (float)t, &s, &c); twr[t] = c; twi[t] = s; }
  const int dd = t & 63, r4 = t >> 6;
  const float2* fqp = fq + ((size_t)bh * FW) * D_ + d0;
  for (int it = 0; it < 17; ++it) {
    const int q = (it << 2) + r4;
    if (q < FW) {
      const float2 v = fqp[(size_t)q * D_ + dd];
      re[(q << 6) + dd] = v.x; im[(q << 6) + dd] = v.y;
    }
  }
  __syncthreads();
  // Hermitian extension: bins 65..127 = conj(bin 128-q)
  for (int it = 0; it < 16; ++it) {
    const int g = it * TPB + t;
    if (g < 63 * 64) {
      const int qq = 65 + (g >> 6), d2 = g & 63;
      re[(qq << 6) + d2] =  re[((128 - qq) << 6) + d2];
      im[(qq << 6) + d2] = -im[((128 - qq) << 6) + d2];
    }
  }
  __syncthreads();
  // inverse DIF (natural-in, bitrev-out), conj twiddles
  for (int s = 0; s < 7; ++s) {
    const int half = 64 >> s;
    for (int it = 0; it < 16; ++it) {
      const int g = it * TPB + t;
      const int d2 = g & 63, m = g >> 6;
      const int blk = m >> (6 - s), k = m & (half - 1);
      const int ia = (blk << (7 - s)) + k, ib = ia + half;
      const float tr = twr[k << s], ti = twi[k << s];
      const int pa = (ia << 6) + d2, pb = (ib << 6) + d2;
      const float arr = re[pa], aii = im[pa];
      const float brr = re[pb], bii = im[pb];
      re[pa] = arr + brr; im[pa] = aii + bii;
      const float dr = arr - brr, di = aii - bii;
      re[pb] = dr * tr + di * ti;       // (dr + i di) * (tr - i ti)
      im[pb] = di * tr - dr * ti;
    }
    __syncthreads();
  }
  const float sc = 0.0078125f;  // 1/128 (ortho inverse)
  const size_t base = (size_t)bh * (W_ * D_) + d0;
  for (int it = 0; it < 32; ++it) {
    const int w = (it << 2) + r4;
    const int j = __brev((unsigned)w) >> 25;
    out[base + w * D_ + dd] = re[(j << 6) + dd] * sc + x[base + w * D_ + dd];
  }
}

// ---------------------------------------------------------------------------
extern "C" void kernel_launch(void* const* d_in, const int* in_sizes, int n_in,
                              void* d_out, int out_size, void* d_ws, size_t ws_size,
                              hipStream_t stream) {
  const float* x   = (const float*)d_in[0];
  const float* w1r = (const float*)d_in[1];
  const float* w1i = (const float*)d_in[2];
  const float* b1  = (const float*)d_in[3];
  const float* w2r = (const float*)d_in[4];
  const float* w2i = (const float*)d_in[5];
  const float* b2  = (const float*)d_in[6];
  float2* fq = (float2*)d_ws;
  float* out = (float*)d_out;

  const size_t need = (size_t)BH_ * FW * D_ * sizeof(float2);  // 204,472,320 B
  if (ws_size < need) {
    fprintf(stderr, "kernel_launch: ws too small (%zu < %zu)\n", ws_size, need);
    return;
  }

  const int FFT_SMEM = (8192 * 2 + 128) * 4;                       // 66,048 B
  const int MLP_SMEM = (96 * 97 + 64 * 97 + 96) * 8 + 64 * 97 * 4; // 149,760 B
  hipFuncSetAttribute((const void*)k_fwd_w, hipFuncAttributeMaxDynamicSharedMemorySize, FFT_SMEM);
  hipFuncSetAttribute((const void*)k_fwd_h, hipFuncAttributeMaxDynamicSharedMemorySize, FFT_SMEM);
  hipFuncSetAttribute((const void*)k_mlp,   hipFuncAttributeMaxDynamicSharedMemorySize, MLP_SMEM);
  hipFuncSetAttribute((const void*)k_inv_h, hipFuncAttributeMaxDynamicSharedMemorySize, FFT_SMEM);
  hipFuncSetAttribute((const void*)k_inv_w, hipFuncAttributeMaxDynamicSharedMemorySize, FFT_SMEM);

  k_fwd_w<<<dim3(BH_, 12), TPB, FFT_SMEM, stream>>>(x, fq);
  k_fwd_h<<<dim3(B_, FW, 12), TPB, FFT_SMEM, stream>>>(fq);
  k_mlp<<<dim3(4160), TPB, MLP_SMEM, stream>>>(fq, w1r, w1i, b1, w2r, w2i, b2);
  k_inv_h<<<dim3(B_, FW, 12), TPB, FFT_SMEM, stream>>>(fq);
  k_inv_w<<<dim3(BH_, 12), TPB, FFT_SMEM, stream>>>(fq, x, out);
}

// Round 2
// 779.219 us; speedup vs baseline: 1.9431x; 1.9431x over previous
//
#include <hip/hip_runtime.h>
#include <hip/hip_bf16.h>
#include <cstdio>

#define TPB 256
#define B_ 4
#define H_ 128
#define W_ 128
#define D_ 768
#define FW 65
#define BH_ 512                  // B_*H_
#define THRESH_ 0.01f
#define NEG_TWO_PI_OVER_128 (-0.04908738521234052f)

typedef short bf16x8 __attribute__((ext_vector_type(8)));
typedef float f32x4 __attribute__((ext_vector_type(4)));

// freq buffer layout (in d_ws): float2[(bh*65 + fw)*768 + d]
// point P in [0, 512*65*8): base float2 offset = P*96; as float: P*192 + col
// (col = 2o+t interleaved re/im).

// ---------------------------------------------------------------------------
// K0: pack complex weights into bf16 B-fragment order + build Wc block form.
//   Wc[k=2c+s][n=2o+t]:  s=0: (t==0? wr[o][c] : wi[o][c])
//                        s=1: (t==0? -wi[o][c] : wr[o][c])
//   storage (bf16): wp[L*36864 + (((n*6 + (k>>5))*4 + ((k>>3)&3))*8 + (k&7))]
// so a lane reads its 8-k fragment as one 16B chunk.
// ---------------------------------------------------------------------------
__global__ __launch_bounds__(TPB) void k_wpack(const float* __restrict__ w1r,
                                               const float* __restrict__ w1i,
                                               const float* __restrict__ w2r,
                                               const float* __restrict__ w2i,
                                               unsigned short* __restrict__ wp) {
  const int tid = blockIdx.x * TPB + threadIdx.x;
  if (tid >= 2 * 36864) return;
  const int L = tid / 36864, rem = tid % 36864;
  const int n = rem / 192, k = rem % 192;
  const int c = k >> 1, s = k & 1, o = n >> 1, t = n & 1;
  const float* wr = L ? w2r : w1r;
  const float* wi = L ? w2i : w1i;
  const float val = (s == 0) ? (t == 0 ? wr[o * 96 + c] : wi[o * 96 + c])
                             : (t == 0 ? -wi[o * 96 + c] : wr[o * 96 + c]);
  __hip_bfloat16 h = __float2bfloat16(val);
  const int idx = ((n * 6 + (k >> 5)) * 4 + ((k >> 3) & 3)) * 8 + (k & 7);
  wp[L * 36864 + idx] = *(unsigned short*)&h;
}

// ---------------------------------------------------------------------------
// K1a: forward FFT over W (real input), keep bins 0..64, scale 1/128.
// ---------------------------------------------------------------------------
__global__ __launch_bounds__(TPB) void k_fwd_w(const float* __restrict__ x,
                                               float2* __restrict__ fq) {
  extern __shared__ float sm[];
  float* re  = sm;
  float* im  = sm + 8192;
  float* twr = sm + 16384;
  float* twi = sm + 16448;
  const int t  = threadIdx.x;
  const int bh = blockIdx.x;
  const int d0 = blockIdx.y << 6;
  if (t < 64) { float s, c; __sincosf(NEG_TWO_PI_OVER_128 * (float)t, &s, &c); twr[t] = c; twi[t] = s; }
  const float* xp = x + (size_t)bh * (W_ * D_) + d0;
  const int dd = t & 63, r4 = t >> 6;
  for (int it = 0; it < 32; ++it) {
    const int w = (it << 2) + r4;
    re[(w << 6) + dd] = xp[w * D_ + dd];
    im[(w << 6) + dd] = 0.f;
  }
  __syncthreads();
  for (int s = 0; s < 7; ++s) {
    const int half = 64 >> s;
    for (int it = 0; it < 16; ++it) {
      const int g = it * TPB + t;
      const int d2 = g & 63, m = g >> 6;
      const int blk = m >> (6 - s), k = m & (half - 1);
      const int ia = (blk << (7 - s)) + k, ib = ia + half;
      const float tr = twr[k << s], ti = twi[k << s];
      const int pa = (ia << 6) + d2, pb = (ib << 6) + d2;
      const float arr = re[pa], aii = im[pa];
      const float brr = re[pb], bii = im[pb];
      re[pa] = arr + brr; im[pa] = aii + bii;
      const float dr = arr - brr, di = aii - bii;
      re[pb] = dr * tr - di * ti;
      im[pb] = dr * ti + di * tr;
    }
    __syncthreads();
  }
  const float sc = 0.0078125f;  // 1/128
  float2* fqp = fq + ((size_t)bh * FW) * D_ + d0;
  for (int it = 0; it < 17; ++it) {
    const int g = it * TPB + t;
    if (g < FW * 64) {
      const int q = g >> 6, d2 = g & 63;
      const int j = __brev((unsigned)q) >> 25;
      fqp[(size_t)q * D_ + d2] = make_float2(re[(j << 6) + d2] * sc, im[(j << 6) + d2] * sc);
    }
  }
}

// ---------------------------------------------------------------------------
// K1b: forward complex FFT over H, in-place; output bit-reversed in H.
// ---------------------------------------------------------------------------
__global__ __launch_bounds__(TPB) void k_fwd_h(float2* __restrict__ fq) {
  extern __shared__ float sm[];
  float* re  = sm;
  float* im  = sm + 8192;
  float* twr = sm + 16384;
  float* twi = sm + 16448;
  const int t  = threadIdx.x;
  const int b  = blockIdx.x;
  const int fw = blockIdx.y;
  const int d0 = blockIdx.z << 6;
  if (t < 64) { float s, c; __sincosf(NEG_TWO_PI_OVER_128 * (float)t, &s, &c); twr[t] = c; twi[t] = s; }
  const int dd = t & 63, r4 = t >> 6;
  float2* base = fq + ((size_t)(b * H_) * FW + fw) * D_ + d0;
  for (int it = 0; it < 32; ++it) {
    const int h = (it << 2) + r4;
    const float2 v = base[(size_t)h * (FW * D_) + dd];
    re[(h << 6) + dd] = v.x; im[(h << 6) + dd] = v.y;
  }
  __syncthreads();
  for (int s = 0; s < 7; ++s) {
    const int half = 64 >> s;
    for (int it = 0; it < 16; ++it) {
      const int g = it * TPB + t;
      const int d2 = g & 63, m = g >> 6;
      const int blk = m >> (6 - s), k = m & (half - 1);
      const int ia = (blk << (7 - s)) + k, ib = ia + half;
      const float tr = twr[k << s], ti = twi[k << s];
      const int pa = (ia << 6) + d2, pb = (ib << 6) + d2;
      const float arr = re[pa], aii = im[pa];
      const float brr = re[pb], bii = im[pb];
      re[pa] = arr + brr; im[pa] = aii + bii;
      const float dr = arr - brr, di = aii - bii;
      re[pb] = dr * tr - di * ti;
      im[pb] = dr * ti + di * tr;
    }
    __syncthreads();
  }
  for (int it = 0; it < 32; ++it) {
    const int h = (it << 2) + r4;
    base[(size_t)h * (FW * D_) + dd] = make_float2(re[(h << 6) + dd], im[(h << 6) + dd]);
  }
}

// ---------------------------------------------------------------------------
// K2: MFMA MLP. One WG = 4 waves, M-tile = 128 points, wave w owns cols
// [48w, 48w+48). Z tile bf16 in LDS [128][192], XOR-swizzled
// (byte ^= (row&7)<<4) so stride-384B A-reads are conflict-minimal.
// Hidden overwrites Z between barriers. In-place on fq.
// ---------------------------------------------------------------------------
__global__ __launch_bounds__(TPB, 2) void k_mlp_mfma(float* __restrict__ fqf,
    const bf16x8* __restrict__ wpb,   // packed bf16 weights (layer stride 4608 chunks)
    const float* __restrict__ b1, const float* __restrict__ b2) {
  __shared__ __align__(16) char lds[49152];   // 128 rows * 384 B
  const int t  = threadIdx.x;
  const int wv = t >> 6;
  const int l  = t & 63;
  const int c16 = l & 15, g = l >> 4, low3 = l & 7;
  const int n0 = wv * 48;
  const int P0 = blockIdx.x << 7;

  // ---- stage Z -> LDS (bf16, swizzled) ----
  const float4* src = (const float4*)(fqf + (size_t)P0 * 192);
#pragma unroll
  for (int it = 0; it < 24; ++it) {
    const int q = it * TPB + t;          // 6144 float4s
    const int row = q / 48, f = q % 48;
    const float4 v = src[q];
    __hip_bfloat162 h01 = __float22bfloat162_rn(make_float2(v.x, v.y));
    __hip_bfloat162 h23 = __float22bfloat162_rn(make_float2(v.z, v.w));
    const uint2 u = make_uint2(*(unsigned*)&h01, *(unsigned*)&h23);
    *(uint2*)(lds + row * 384 + ((f * 8) ^ ((row & 7) << 4))) = u;
  }
  __syncthreads();

  f32x4 acc[8][3];
  // bias for this lane's 3 columns
  float bs0 = b1[n0 + c16], bs1 = b1[n0 + 16 + c16], bs2 = b1[n0 + 32 + c16];

  // ================= layer 1 =================
#pragma unroll
  for (int mt = 0; mt < 8; ++mt)
#pragma unroll
    for (int np = 0; np < 3; ++np) acc[mt][np] = (f32x4)0.f;

  for (int kk = 0; kk < 6; ++kk) {
    bf16x8 a[8];
#pragma unroll
    for (int mt = 0; mt < 8; ++mt) {
      const int row = (mt << 4) + c16;
      a[mt] = *(const bf16x8*)(lds + row * 384 + ((kk * 64 + g * 16) ^ (low3 << 4)));
    }
    bf16x8 bfr[3];
#pragma unroll
    for (int np = 0; np < 3; ++np) {
      const int n = n0 + np * 16 + c16;
      bfr[np] = wpb[(n * 6 + kk) * 4 + g];
    }
#pragma unroll
    for (int mt = 0; mt < 8; ++mt)
#pragma unroll
      for (int np = 0; np < 3; ++np)
        acc[mt][np] = __builtin_amdgcn_mfma_f32_16x16x32_bf16(a[mt], bfr[np], acc[mt][np], 0, 0, 0);
  }

  __syncthreads();  // everyone done reading Z
  // bias + ReLU -> bf16 hidden, overwrite Z buffer (same swizzled layout)
#pragma unroll
  for (int mt = 0; mt < 8; ++mt)
#pragma unroll
    for (int np = 0; np < 3; ++np) {
      const int col = n0 + np * 16 + c16;
      const float bb = np == 0 ? bs0 : (np == 1 ? bs1 : bs2);
#pragma unroll
      for (int r = 0; r < 4; ++r) {
        const int row = (mt << 4) + (g << 2) + r;
        const float vv = fmaxf(acc[mt][np][r] + bb, 0.f);
        __hip_bfloat16 hb = __float2bfloat16(vv);
        *(unsigned short*)(lds + row * 384 + ((2 * col) ^ ((row & 7) << 4))) = *(unsigned short*)&hb;
      }
    }
  __syncthreads();

  // ================= layer 2 =================
  bs0 = b2[n0 + c16]; bs1 = b2[n0 + 16 + c16]; bs2 = b2[n0 + 32 + c16];
#pragma unroll
  for (int mt = 0; mt < 8; ++mt)
#pragma unroll
    for (int np = 0; np < 3; ++np) acc[mt][np] = (f32x4)0.f;

  const bf16x8* wpb2 = wpb + 4608;
  for (int kk = 0; kk < 6; ++kk) {
    bf16x8 a[8];
#pragma unroll
    for (int mt = 0; mt < 8; ++mt) {
      const int row = (mt << 4) + c16;
      a[mt] = *(const bf16x8*)(lds + row * 384 + ((kk * 64 + g * 16) ^ (low3 << 4)));
    }
    bf16x8 bfr[3];
#pragma unroll
    for (int np = 0; np < 3; ++np) {
      const int n = n0 + np * 16 + c16;
      bfr[np] = wpb2[(n * 6 + kk) * 4 + g];
    }
#pragma unroll
    for (int mt = 0; mt < 8; ++mt)
#pragma unroll
      for (int np = 0; np < 3; ++np)
        acc[mt][np] = __builtin_amdgcn_mfma_f32_16x16x32_bf16(a[mt], bfr[np], acc[mt][np], 0, 0, 0);
  }

  // bias + softshrink -> global f32 (in-place on fq)
#pragma unroll
  for (int mt = 0; mt < 8; ++mt)
#pragma unroll
    for (int np = 0; np < 3; ++np) {
      const int col = n0 + np * 16 + c16;
      const float bb = np == 0 ? bs0 : (np == 1 ? bs1 : bs2);
#pragma unroll
      for (int r = 0; r < 4; ++r) {
        const int row = (mt << 4) + (g << 2) + r;
        float vv = acc[mt][np][r] + bb;
        vv = (vv > THRESH_) ? (vv - THRESH_) : ((vv < -THRESH_) ? (vv + THRESH_) : 0.f);
        fqf[(size_t)(P0 + row) * 192 + col] = vv;
      }
    }
}

// ---------------------------------------------------------------------------
// K3a: inverse complex FFT over H (DIT, bitrev-in natural-out), in-place.
// ---------------------------------------------------------------------------
__global__ __launch_bounds__(TPB) void k_inv_h(float2* __restrict__ fq) {
  extern __shared__ float sm[];
  float* re  = sm;
  float* im  = sm + 8192;
  float* twr = sm + 16384;
  float* twi = sm + 16448;
  const int t  = threadIdx.x;
  const int b  = blockIdx.x;
  const int fw = blockIdx.y;
  const int d0 = blockIdx.z << 6;
  if (t < 64) { float s, c; __sincosf(NEG_TWO_PI_OVER_128 * (float)t, &s, &c); twr[t] = c; twi[t] = s; }
  const int dd = t & 63, r4 = t >> 6;
  float2* base = fq + ((size_t)(b * H_) * FW + fw) * D_ + d0;
  for (int it = 0; it < 32; ++it) {
    const int h = (it << 2) + r4;
    const float2 v = base[(size_t)h * (FW * D_) + dd];
    re[(h << 6) + dd] = v.x; im[(h << 6) + dd] = v.y;
  }
  __syncthreads();
  for (int s = 0; s < 7; ++s) {
    const int half = 1 << s;
    for (int it = 0; it < 16; ++it) {
      const int g = it * TPB + t;
      const int d2 = g & 63, m = g >> 6;
      const int blk = m >> s, k = m & (half - 1);
      const int ia = (blk << (s + 1)) + k, ib = ia + half;
      const int idx = k << (6 - s);
      const float tr = twr[idx], ti = twi[idx];
      const int pa = (ia << 6) + d2, pb = (ib << 6) + d2;
      const float brr = re[pb], bii = im[pb];
      const float xr = brr * tr + bii * ti;
      const float xi = bii * tr - brr * ti;
      const float arr = re[pa], aii = im[pa];
      re[pa] = arr + xr; im[pa] = aii + xi;
      re[pb] = arr - xr; im[pb] = aii - xi;
    }
    __syncthreads();
  }
  for (int it = 0; it < 32; ++it) {
    const int h = (it << 2) + r4;
    base[(size_t)h * (FW * D_) + dd] = make_float2(re[(h << 6) + dd], im[(h << 6) + dd]);
  }
}

// ---------------------------------------------------------------------------
// K3b: Hermitian-extend 65->128, inverse DIF over W, +skip, write out.
// ---------------------------------------------------------------------------
__global__ __launch_bounds__(TPB) void k_inv_w(const float2* __restrict__ fq,
                                               const float* __restrict__ x,
                                               float* __restrict__ out) {
  extern __shared__ float sm[];
  float* re  = sm;
  float* im  = sm + 8192;
  float* twr = sm + 16384;
  float* twi = sm + 16448;
  const int t  = threadIdx.x;
  const int bh = blockIdx.x;
  const int d0 = blockIdx.y << 6;
  if (t < 64) { float s, c; __sincosf(NEG_TWO_PI_OVER_128 * (float)t, &s, &c); twr[t] = c; twi[t] = s; }
  const int dd = t & 63, r4 = t >> 6;
  const float2* fqp = fq + ((size_t)bh * FW) * D_ + d0;
  for (int it = 0; it < 17; ++it) {
    const int q = (it << 2) + r4;
    if (q < FW) {
      const float2 v = fqp[(size_t)q * D_ + dd];
      re[(q << 6) + dd] = v.x; im[(q << 6) + dd] = v.y;
    }
  }
  __syncthreads();
  for (int it = 0; it < 16; ++it) {
    const int g = it * TPB + t;
    if (g < 63 * 64) {
      const int qq = 65 + (g >> 6), d2 = g & 63;
      re[(qq << 6) + d2] =  re[((128 - qq) << 6) + d2];
      im[(qq << 6) + d2] = -im[((128 - qq) << 6) + d2];
    }
  }
  __syncthreads();
  for (int s = 0; s < 7; ++s) {
    const int half = 64 >> s;
    for (int it = 0; it < 16; ++it) {
      const int g = it * TPB + t;
      const int d2 = g & 63, m = g >> 6;
      const int blk = m >> (6 - s), k = m & (half - 1);
      const int ia = (blk << (7 - s)) + k, ib = ia + half;
      const float tr = twr[k << s], ti = twi[k << s];
      const int pa = (ia << 6) + d2, pb = (ib << 6) + d2;
      const float arr = re[pa], aii = im[pa];
      const float brr = re[pb], bii = im[pb];
      re[pa] = arr + brr; im[pa] = aii + bii;
      const float dr = arr - brr, di = aii - bii;
      re[pb] = dr * tr + di * ti;
      im[pb] = di * tr - dr * ti;
    }
    __syncthreads();
  }
  const float sc = 0.0078125f;
  const size_t base = (size_t)bh * (W_ * D_) + d0;
  for (int it = 0; it < 32; ++it) {
    const int w = (it << 2) + r4;
    const int j = __brev((unsigned)w) >> 25;
    out[base + w * D_ + dd] = re[(j << 6) + dd] * sc + x[base + w * D_ + dd];
  }
}

// ---------------------------------------------------------------------------
extern "C" void kernel_launch(void* const* d_in, const int* in_sizes, int n_in,
                              void* d_out, int out_size, void* d_ws, size_t ws_size,
                              hipStream_t stream) {
  const float* x   = (const float*)d_in[0];
  const float* w1r = (const float*)d_in[1];
  const float* w1i = (const float*)d_in[2];
  const float* b1  = (const float*)d_in[3];
  const float* w2r = (const float*)d_in[4];
  const float* w2i = (const float*)d_in[5];
  const float* b2  = (const float*)d_in[6];
  float2* fq = (float2*)d_ws;
  float* out = (float*)d_out;

  const size_t need = (size_t)BH_ * FW * D_ * sizeof(float2);  // 204,472,320 B
  if (ws_size < need) {
    fprintf(stderr, "kernel_launch: ws too small (%zu < %zu)\n", ws_size, need);
    return;
  }

  // packed bf16 weights live at the start of d_out (k_inv_w fully overwrites
  // d_out afterwards, so this is safe scratch).
  unsigned short* wp = (unsigned short*)d_out;

  const int FFT_SMEM = (8192 * 2 + 128) * 4;  // 66,048 B
  hipFuncSetAttribute((const void*)k_fwd_w, hipFuncAttributeMaxDynamicSharedMemorySize, FFT_SMEM);
  hipFuncSetAttribute((const void*)k_fwd_h, hipFuncAttributeMaxDynamicSharedMemorySize, FFT_SMEM);
  hipFuncSetAttribute((const void*)k_inv_h, hipFuncAttributeMaxDynamicSharedMemorySize, FFT_SMEM);
  hipFuncSetAttribute((const void*)k_inv_w, hipFuncAttributeMaxDynamicSharedMemorySize, FFT_SMEM);

  k_wpack<<<dim3(288), TPB, 0, stream>>>(w1r, w1i, w2r, w2i, wp);
  k_fwd_w<<<dim3(BH_, 12), TPB, FFT_SMEM, stream>>>(x, fq);
  k_fwd_h<<<dim3(B_, FW, 12), TPB, FFT_SMEM, stream>>>(fq);
  k_mlp_mfma<<<dim3(2080), TPB, 0, stream>>>((float*)fq, (const bf16x8*)wp, b1, b2);
  k_inv_h<<<dim3(B_, FW, 12), TPB, FFT_SMEM, stream>>>(fq);
  k_inv_w<<<dim3(BH_, 12), TPB, FFT_SMEM, stream>>>(fq, x, out);
}

// Round 3
// 354.657 us; speedup vs baseline: 4.2691x; 2.1971x over previous
//
#include <hip/hip_runtime.h>
#include <hip/hip_bf16.h>
#include <cstdio>

#define TPB 256
#define B_ 4
#define H_ 128
#define W_ 128
#define D_ 768
#define FW 65
#define BH_ 512                  // B_*H_
#define THRESH_ 0.01f
#define NEG_TWO_PI_OVER_128 (-0.04908738521234052f)

typedef short bf16x8 __attribute__((ext_vector_type(8)));
typedef float f32x4 __attribute__((ext_vector_type(4)));

// fq (in d_ws): one u32 per (point, channel) = packed (bf16 re, bf16 im)
//   u32 index = ((bh*65 + fw))*768 + d   ;   point-block P: u32 idx = P*96
// Mixed-radix 128 = 4*4*4*2 DIF: slot(k) = digit-reverse:
//   s(k) = ((k&3)<<5) | (((k>>2)&3)<<3) | (((k>>4)&3)<<1) | ((k>>6)&1)

__device__ __forceinline__ unsigned pk(float lo, float hi) {
  __hip_bfloat162 h2 = __float22bfloat162_rn(make_float2(lo, hi));
  return *(unsigned*)&h2;
}
__device__ __forceinline__ float2 upk(unsigned u) {
  return __bfloat1622float2(*(__hip_bfloat162*)&u);
}
__device__ __forceinline__ int drev(int k) {
  return ((k & 3) << 5) | (((k >> 2) & 3) << 3) | (((k >> 4) & 3) << 1) | ((k >> 6) & 1);
}

// radix-4 DIF butterfly, in-place on 4 LDS slots. FWD: e^-i kernel; !FWD: e^+i
// (twiddle table holds e^{-i 2pi t/128}; !FWD conjugates it).
template <bool FWD>
__device__ __forceinline__ void bfly4(float* re, float* im, int i0, int i1, int i2, int i3,
                                      float c1, float s1, float c2, float s2, float c3, float s3) {
  const float x0r = re[i0], x0i = im[i0], x1r = re[i1], x1i = im[i1];
  const float x2r = re[i2], x2i = im[i2], x3r = re[i3], x3i = im[i3];
  const float v0r = x0r + x2r, v0i = x0i + x2i, v2r = x0r - x2r, v2i = x0i - x2i;
  const float v1r = x1r + x3r, v1i = x1i + x3i, v3r = x1r - x3r, v3i = x1i - x3i;
  float u1r, u1i, u3r, u3i;
  if (FWD) { u1r = v2r + v3i; u1i = v2i - v3r; u3r = v2r - v3i; u3i = v2i + v3r; }
  else     { u1r = v2r - v3i; u1i = v2i + v3r; u3r = v2r + v3i; u3i = v2i - v3r; }
  const float u2r = v0r - v1r, u2i = v0i - v1i;
  re[i0] = v0r + v1r; im[i0] = v0i + v1i;
  re[i1] = u1r * c1 - u1i * s1; im[i1] = u1r * s1 + u1i * c1;
  re[i2] = u2r * c2 - u2i * s2; im[i2] = u2r * s2 + u2i * c2;
  re[i3] = u3r * c3 - u3i * s3; im[i3] = u3r * s3 + u3i * c3;
}

// one DIF radix-4 stage over [128 slots][32 cols]; 32 groups x 32 cols / 256 thr
template <bool FWD>
__device__ __forceinline__ void run_stage(float* re, float* im, int t,
                                          int npmask, int npbits, int span, int twm,
                                          const float* twr, const float* twi) {
#pragma unroll
  for (int it = 0; it < 4; ++it) {
    const int gid = it * TPB + t;
    const int cc = gid & 31, g = gid >> 5;
    const int np = g & npmask, blk = g >> npbits;
    const int base = blk * (span << 2) + np;
    const int i0 = base * 32 + cc, i1 = (base + span) * 32 + cc;
    const int i2 = (base + 2 * span) * 32 + cc, i3 = (base + 3 * span) * 32 + cc;
    const int tb = np * twm;
    float c1 = twr[tb], s1 = twi[tb];
    float c2 = twr[2 * tb], s2 = twi[2 * tb];
    float c3 = twr[3 * tb], s3 = twi[3 * tb];
    if (!FWD) { s1 = -s1; s2 = -s2; s3 = -s3; }
    bfly4<FWD>(re, im, i0, i1, i2, i3, c1, s1, c2, s2, c3, s3);
  }
  __syncthreads();
}

// inverse (DIT) of a DIF radix-4 stage: conj twiddle first, then inverse DFT4
__device__ __forceinline__ void run_stage_dit(float* re, float* im, int t,
                                              int npmask, int npbits, int span, int twm,
                                              const float* twr, const float* twi) {
#pragma unroll
  for (int it = 0; it < 4; ++it) {
    const int gid = it * TPB + t;
    const int cc = gid & 31, g = gid >> 5;
    const int np = g & npmask, blk = g >> npbits;
    const int base = blk * (span << 2) + np;
    const int i0 = base * 32 + cc, i1 = (base + span) * 32 + cc;
    const int i2 = (base + 2 * span) * 32 + cc, i3 = (base + 3 * span) * 32 + cc;
    const int tb = np * twm;
    const float c1 = twr[tb], s1 = twi[tb];
    const float c2 = twr[2 * tb], s2 = twi[2 * tb];
    const float c3 = twr[3 * tb], s3 = twi[3 * tb];
    const float t0r = re[i0], t0i = im[i0];
    const float y1r = re[i1], y1i = im[i1], y2r = re[i2], y2i = im[i2], y3r = re[i3], y3i = im[i3];
    const float t1r = y1r * c1 + y1i * s1, t1i = y1i * c1 - y1r * s1;
    const float t2r = y2r * c2 + y2i * s2, t2i = y2i * c2 - y2r * s2;
    const float t3r = y3r * c3 + y3i * s3, t3i = y3i * c3 - y3r * s3;
    const float w0r = t0r + t2r, w0i = t0i + t2i, w2r = t0r - t2r, w2i = t0i - t2i;
    const float w1r = t1r + t3r, w1i = t1i + t3i, w3r = t1r - t3r, w3i = t1i - t3i;
    re[i0] = w0r + w1r; im[i0] = w0i + w1i;
    re[i1] = w2r - w3i; im[i1] = w2i + w3r;   // x1 = w2 + i w3
    re[i2] = w0r - w1r; im[i2] = w0i - w1i;
    re[i3] = w2r + w3i; im[i3] = w2i - w3r;   // x3 = w2 - i w3
  }
  __syncthreads();
}

__device__ __forceinline__ void run_r2(float* re, float* im, int t) {
#pragma unroll
  for (int it = 0; it < 8; ++it) {
    const int pid = it * TPB + t;
    const int cc = pid & 31, p = pid >> 5;
    const int i0 = (2 * p) * 32 + cc, i1 = i0 + 32;
    const float ar = re[i0], ai = im[i0], br = re[i1], bi = im[i1];
    re[i0] = ar + br; im[i0] = ai + bi;
    re[i1] = ar - br; im[i1] = ai - bi;
  }
  __syncthreads();
}

#define TW_INIT() do { if (t < 128) { float s_, c_; \
    __sincosf(NEG_TWO_PI_OVER_128 * (float)t, &s_, &c_); twr[t] = c_; twi[t] = s_; } } while (0)

// ---------------------------------------------------------------------------
// K0: pack complex weights into bf16 B-fragment order (block form Wc).
// ---------------------------------------------------------------------------
__global__ __launch_bounds__(TPB) void k_wpack(const float* __restrict__ w1r,
                                               const float* __restrict__ w1i,
                                               const float* __restrict__ w2r,
                                               const float* __restrict__ w2i,
                                               unsigned short* __restrict__ wp) {
  const int tid = blockIdx.x * TPB + threadIdx.x;
  if (tid >= 2 * 36864) return;
  const int L = tid / 36864, rem = tid % 36864;
  const int n = rem / 192, k = rem % 192;
  const int c = k >> 1, s = k & 1, o = n >> 1, t = n & 1;
  const float* wr = L ? w2r : w1r;
  const float* wi = L ? w2i : w1i;
  const float val = (s == 0) ? (t == 0 ? wr[o * 96 + c] : wi[o * 96 + c])
                             : (t == 0 ? -wi[o * 96 + c] : wr[o * 96 + c]);
  __hip_bfloat16 h = __float2bfloat16(val);
  const int idx = ((n * 6 + (k >> 5)) * 4 + ((k >> 3) & 3)) * 8 + (k & 7);
  wp[L * 36864 + idx] = *(unsigned short*)&h;
}

// ---------------------------------------------------------------------------
// K1a: forward rFFT over W via real-pair packing: z = x[:,2c] + i x[:,2c+1].
// grid (512, 12), 64 d per WG (32 complex cols). Writes bf16 fq, bins 0..64.
// ---------------------------------------------------------------------------
__global__ __launch_bounds__(TPB) void k_fwd_w(const float* __restrict__ x,
                                               unsigned* __restrict__ fq) {
  __shared__ float re[4096], im[4096], twr[128], twi[128];
  const int t = threadIdx.x;
  const int bh = blockIdx.x;
  const int d0 = blockIdx.y << 6;
  TW_INIT();
  const float2* xp = (const float2*)(x + (size_t)bh * 98304 + d0);
#pragma unroll
  for (int it = 0; it < 16; ++it) {
    const int w = (it << 3) + (t >> 5), c = t & 31;
    const float2 v = xp[w * 384 + c];
    re[w * 32 + c] = v.x; im[w * 32 + c] = v.y;
  }
  __syncthreads();
  run_stage<true>(re, im, t, 31, 5, 32, 1, twr, twi);
  run_stage<true>(re, im, t, 7, 3, 8, 4, twr, twi);
  run_stage<true>(re, im, t, 1, 1, 2, 16, twr, twi);
  run_r2(re, im, t);
  // unpack pair + ortho scale (1/128) and the 1/2 from unpacking
#pragma unroll
  for (int it = 0; it < 9; ++it) {
    const int idx = it * TPB + t;
    if (idx < FW * 32) {
      const int q = idx >> 5, c = idx & 31;
      const int sq = drev(q), sm = drev((128 - q) & 127);
      const float a = re[sq * 32 + c], b = im[sq * 32 + c];
      const float cr = re[sm * 32 + c], dr = -im[sm * 32 + c];  // Q = conj(Z[128-q])
      const float hsc = 0.00390625f;  // 0.5 * (1/128)
      const float xer = (a + cr) * hsc, xei = (b + dr) * hsc;
      const float xor_ = (b - dr) * hsc, xoi = (cr - a) * hsc;
      *(uint2*)(fq + (size_t)(bh * FW + q) * 768 + d0 + 2 * c) =
          make_uint2(pk(xer, xei), pk(xor_, xoi));
    }
  }
}

// ---------------------------------------------------------------------------
// K1b: forward complex FFT over H, in-place on bf16 fq; output digit-reversed.
// grid (4, 65, 24), 32 d per WG.
// ---------------------------------------------------------------------------
__global__ __launch_bounds__(TPB) void k_fwd_h(unsigned* __restrict__ fq) {
  __shared__ float re[4096], im[4096], twr[128], twi[128];
  const int t = threadIdx.x;
  const int b = blockIdx.x, fw = blockIdx.y, d0 = blockIdx.z << 5;
  TW_INIT();
  unsigned* fp = fq + (size_t)(b * 128 * FW + fw) * 768 + d0;
#pragma unroll
  for (int it = 0; it < 16; ++it) {
    const int h = (it << 3) + (t >> 5), c = t & 31;
    const float2 v = upk(fp[(size_t)h * (FW * 768) + c]);
    re[h * 32 + c] = v.x; im[h * 32 + c] = v.y;
  }
  __syncthreads();
  run_stage<true>(re, im, t, 31, 5, 32, 1, twr, twi);
  run_stage<true>(re, im, t, 7, 3, 8, 4, twr, twi);
  run_stage<true>(re, im, t, 1, 1, 2, 16, twr, twi);
  run_r2(re, im, t);
#pragma unroll
  for (int it = 0; it < 16; ++it) {
    const int h = (it << 3) + (t >> 5), c = t & 31;
    fp[(size_t)h * (FW * 768) + c] = pk(re[h * 32 + c], im[h * 32 + c]);
  }
}

// ---------------------------------------------------------------------------
// K2: MFMA MLP, in-place on bf16 fq (staging = raw copy; epilogue bf16 store).
// ---------------------------------------------------------------------------
__global__ __launch_bounds__(TPB, 2) void k_mlp_mfma(unsigned* __restrict__ fq,
    const bf16x8* __restrict__ wpb,
    const float* __restrict__ b1, const float* __restrict__ b2) {
  __shared__ __align__(16) char lds[49152];   // 128 rows * 384 B
  const int t  = threadIdx.x;
  const int wv = t >> 6;
  const int l  = t & 63;
  const int c16 = l & 15, g = l >> 4, low3 = l & 7;
  const int n0 = wv * 48;
  const int P0 = blockIdx.x << 7;

  // stage Z tile (bf16, swizzled): 128 rows x 384 B
  const uint4* src = (const uint4*)(fq + (size_t)P0 * 96);
#pragma unroll
  for (int it = 0; it < 12; ++it) {
    const int q = it * TPB + t;                 // 3072 uint4s
    const int row = q / 24, f = q % 24;
    *(uint4*)(lds + row * 384 + ((f * 16) ^ ((row & 7) << 4))) = src[q];
  }
  __syncthreads();

  f32x4 acc[8][3];
  float bs0 = b1[n0 + c16], bs1 = b1[n0 + 16 + c16], bs2 = b1[n0 + 32 + c16];

  // ---- layer 1 ----
#pragma unroll
  for (int mt = 0; mt < 8; ++mt)
#pragma unroll
    for (int np = 0; np < 3; ++np) acc[mt][np] = (f32x4)0.f;
  for (int kk = 0; kk < 6; ++kk) {
    bf16x8 a[8];
#pragma unroll
    for (int mt = 0; mt < 8; ++mt) {
      const int row = (mt << 4) + c16;
      a[mt] = *(const bf16x8*)(lds + row * 384 + ((kk * 64 + g * 16) ^ (low3 << 4)));
    }
    bf16x8 bfr[3];
#pragma unroll
    for (int np = 0; np < 3; ++np) bfr[np] = wpb[((n0 + np * 16 + c16) * 6 + kk) * 4 + g];
#pragma unroll
    for (int mt = 0; mt < 8; ++mt)
#pragma unroll
      for (int np = 0; np < 3; ++np)
        acc[mt][np] = __builtin_amdgcn_mfma_f32_16x16x32_bf16(a[mt], bfr[np], acc[mt][np], 0, 0, 0);
  }
  __syncthreads();
  // bias + ReLU -> bf16 hidden (same swizzled layout)
#pragma unroll
  for (int mt = 0; mt < 8; ++mt)
#pragma unroll
    for (int np = 0; np < 3; ++np) {
      const int col = n0 + np * 16 + c16;
      const float bb = np == 0 ? bs0 : (np == 1 ? bs1 : bs2);
#pragma unroll
      for (int r = 0; r < 4; ++r) {
        const int row = (mt << 4) + (g << 2) + r;
        const float vv = fmaxf(acc[mt][np][r] + bb, 0.f);
        __hip_bfloat16 hb = __float2bfloat16(vv);
        *(unsigned short*)(lds + row * 384 + ((2 * col) ^ ((row & 7) << 4))) = *(unsigned short*)&hb;
      }
    }
  __syncthreads();

  // ---- layer 2 ----
  bs0 = b2[n0 + c16]; bs1 = b2[n0 + 16 + c16]; bs2 = b2[n0 + 32 + c16];
#pragma unroll
  for (int mt = 0; mt < 8; ++mt)
#pragma unroll
    for (int np = 0; np < 3; ++np) acc[mt][np] = (f32x4)0.f;
  const bf16x8* wpb2 = wpb + 4608;
  for (int kk = 0; kk < 6; ++kk) {
    bf16x8 a[8];
#pragma unroll
    for (int mt = 0; mt < 8; ++mt) {
      const int row = (mt << 4) + c16;
      a[mt] = *(const bf16x8*)(lds + row * 384 + ((kk * 64 + g * 16) ^ (low3 << 4)));
    }
    bf16x8 bfr[3];
#pragma unroll
    for (int np = 0; np < 3; ++np) bfr[np] = wpb2[((n0 + np * 16 + c16) * 6 + kk) * 4 + g];
#pragma unroll
    for (int mt = 0; mt < 8; ++mt)
#pragma unroll
      for (int np = 0; np < 3; ++np)
        acc[mt][np] = __builtin_amdgcn_mfma_f32_16x16x32_bf16(a[mt], bfr[np], acc[mt][np], 0, 0, 0);
  }
  // bias + softshrink -> bf16 global
  unsigned short* fq16 = (unsigned short*)fq;
#pragma unroll
  for (int mt = 0; mt < 8; ++mt)
#pragma unroll
    for (int np = 0; np < 3; ++np) {
      const int col = n0 + np * 16 + c16;
      const float bb = np == 0 ? bs0 : (np == 1 ? bs1 : bs2);
#pragma unroll
      for (int r = 0; r < 4; ++r) {
        const int row = (mt << 4) + (g << 2) + r;
        float vv = acc[mt][np][r] + bb;
        vv = (vv > THRESH_) ? (vv - THRESH_) : ((vv < -THRESH_) ? (vv + THRESH_) : 0.f);
        __hip_bfloat16 hb = __float2bfloat16(vv);
        fq16[(size_t)(P0 + row) * 192 + col] = *(unsigned short*)&hb;
      }
    }
}

// ---------------------------------------------------------------------------
// K3a: inverse FFT over H: DIT consuming fwd_h's digit-reversed slots,
// natural-order output, unnormalized. In-place bf16.
// ---------------------------------------------------------------------------
__global__ __launch_bounds__(TPB) void k_inv_h(unsigned* __restrict__ fq) {
  __shared__ float re[4096], im[4096], twr[128], twi[128];
  const int t = threadIdx.x;
  const int b = blockIdx.x, fw = blockIdx.y, d0 = blockIdx.z << 5;
  TW_INIT();
  unsigned* fp = fq + (size_t)(b * 128 * FW + fw) * 768 + d0;
#pragma unroll
  for (int it = 0; it < 16; ++it) {
    const int h = (it << 3) + (t >> 5), c = t & 31;
    const float2 v = upk(fp[(size_t)h * (FW * 768) + c]);
    re[h * 32 + c] = v.x; im[h * 32 + c] = v.y;
  }
  __syncthreads();
  run_r2(re, im, t);
  run_stage_dit(re, im, t, 1, 1, 2, 16, twr, twi);
  run_stage_dit(re, im, t, 7, 3, 8, 4, twr, twi);
  run_stage_dit(re, im, t, 31, 5, 32, 1, twr, twi);
#pragma unroll
  for (int it = 0; it < 16; ++it) {
    const int h = (it << 3) + (t >> 5), c = t & 31;
    fp[(size_t)h * (FW * 768) + c] = pk(re[h * 32 + c], im[h * 32 + c]);
  }
}

// ---------------------------------------------------------------------------
// K3b: inverse rFFT over W via pair packing: Z[k] = Ye[k] + i Yo[k] built with
// Hermitian extension at load, inverse-DIF (e^+), slot drev(w) -> sample w,
// scale 1/128, add skip, write f32 out. grid (512, 12).
// ---------------------------------------------------------------------------
__global__ __launch_bounds__(TPB) void k_inv_w(const unsigned* __restrict__ fq,
                                               const float* __restrict__ x,
                                               float* __restrict__ out) {
  __shared__ float re[4096], im[4096], twr[128], twi[128];
  const int t = threadIdx.x;
  const int bh = blockIdx.x;
  const int d0 = blockIdx.y << 6;
  TW_INIT();
#pragma unroll
  for (int it = 0; it < 9; ++it) {
    const int idx = it * TPB + t;
    if (idx < FW * 32) {
      const int q = idx >> 5, c = idx & 31;
      const uint2 vv = *(const uint2*)(fq + (size_t)(bh * FW + q) * 768 + d0 + 2 * c);
      const float2 e = upk(vv.x), o = upk(vv.y);
      re[q * 32 + c] = e.x - o.y; im[q * 32 + c] = e.y + o.x;
      if (q >= 1 && q <= 63) {
        re[(128 - q) * 32 + c] = e.x + o.y;
        im[(128 - q) * 32 + c] = o.x - e.y;
      }
    }
  }
  __syncthreads();
  run_stage<false>(re, im, t, 31, 5, 32, 1, twr, twi);
  run_stage<false>(re, im, t, 7, 3, 8, 4, twr, twi);
  run_stage<false>(re, im, t, 1, 1, 2, 16, twr, twi);
  run_r2(re, im, t);
  const float sc = 0.0078125f;  // 1/128
#pragma unroll
  for (int it = 0; it < 16; ++it) {
    const int w = (it << 3) + (t >> 5), c = t & 31;
    const int s = drev(w);
    const float yr = re[s * 32 + c] * sc, yi = im[s * 32 + c] * sc;
    const size_t fi = (size_t)bh * 49152 + w * 384 + (d0 >> 1) + c;  // float2 idx
    const float2 xv = ((const float2*)x)[fi];
    ((float2*)out)[fi] = make_float2(yr + xv.x, yi + xv.y);
  }
}

// ---------------------------------------------------------------------------
extern "C" void kernel_launch(void* const* d_in, const int* in_sizes, int n_in,
                              void* d_out, int out_size, void* d_ws, size_t ws_size,
                              hipStream_t stream) {
  const float* x   = (const float*)d_in[0];
  const float* w1r = (const float*)d_in[1];
  const float* w1i = (const float*)d_in[2];
  const float* b1  = (const float*)d_in[3];
  const float* w2r = (const float*)d_in[4];
  const float* w2i = (const float*)d_in[5];
  const float* b2  = (const float*)d_in[6];
  unsigned* fq = (unsigned*)d_ws;
  float* out = (float*)d_out;

  const size_t need = (size_t)BH_ * FW * 768 * 4;  // 102,236,160 B
  if (ws_size < need) {
    fprintf(stderr, "kernel_launch: ws too small (%zu < %zu)\n", ws_size, need);
    return;
  }

  // packed bf16 weights at start of d_out (fully overwritten by k_inv_w later)
  unsigned short* wp = (unsigned short*)d_out;

  k_wpack<<<dim3(288), TPB, 0, stream>>>(w1r, w1i, w2r, w2i, wp);
  k_fwd_w<<<dim3(BH_, 12), TPB, 0, stream>>>(x, fq);
  k_fwd_h<<<dim3(B_, FW, 24), TPB, 0, stream>>>(fq);
  k_mlp_mfma<<<dim3(2080), TPB, 0, stream>>>(fq, (const bf16x8*)wp, b1, b2);
  k_inv_h<<<dim3(B_, FW, 24), TPB, 0, stream>>>(fq);
  k_inv_w<<<dim3(BH_, 12), TPB, 0, stream>>>(fq, x, out);
}